// Round 11
// baseline (260.263 us; speedup 1.0000x reference)
//
#include <hip/hip_runtime.h>
#include <hip/hip_bf16.h>
#include <math.h>

#define NB   32768
#define NM   2048
#define NEMB 128
#define NK   8
#define TAU  0.3f
#define FLT_BIG 3.402823466e38f
#define ROWS_PER_WAVE 8
#define ROWSTEP 4096              // 512 blocks x 8 waves = 4096 wave-slots

typedef __attribute__((ext_vector_type(8))) short bf16x8;
typedef __attribute__((ext_vector_type(4))) float f32x4;

// tanh-form GELU: x * sigmoid(2*0.79788456*(x+0.044715 x^3)), branch-free.
__device__ __forceinline__ float gelu_tanh(float x) {
    const float x2 = x * x;
    const float u  = fmaf(0.044715f, x2, 1.0f);
    const float a  = x * u * (-2.3022082f);          // -2*0.79788456*log2(e)
    const float e  = __builtin_amdgcn_exp2f(a);      // exp(-2t)
    const float r  = __builtin_amdgcn_rcpf(e + 1.0f);
    return x * r;                                    // x * sigmoid(2t)
}
// f32 pair -> packed bf16 (RNE): (bf16(hi)<<16)|bf16(lo), 1 v_cvt_pk_bf16_f32
__device__ __forceinline__ unsigned pack2(float lo, float hi) {
    __hip_bfloat162 b = __float22bfloat162_rn(make_float2(lo, hi));
    return *reinterpret_cast<unsigned*>(&b);
}

// DPP helpers: quad_perm xor1=0xB1, xor2=0x4E, row_half_mirror=0x141, row_mirror=0x140
template<int CTRL>
__device__ __forceinline__ unsigned dpp_umin(unsigned v) {
    const unsigned t = (unsigned)__builtin_amdgcn_update_dpp(0, (int)v, CTRL, 0xF, 0xF, true);
    return v < t ? v : t;
}
template<int CTRL>
__device__ __forceinline__ float dpp_fadd(float v) {
    const float t = __int_as_float(__builtin_amdgcn_update_dpp(0, __float_as_int(v), CTRL, 0xF, 0xF, true));
    return v + t;
}

// sorted top-3 insert (values via fmed3, payload via cndmask)
__device__ __forceinline__ void ins3(float (&bd)[3], unsigned (&bp)[3], float d, unsigned p) {
    const bool c0 = d < bd[0], c1 = d < bd[1], c2 = d < bd[2];
    const float n2 = __builtin_amdgcn_fmed3f(d, bd[1], bd[2]);
    const float n1 = __builtin_amdgcn_fmed3f(d, bd[0], bd[1]);
    const float n0 = fminf(d, bd[0]);
    bp[2] = c1 ? bp[1] : (c2 ? p : bp[2]);
    bp[1] = c0 ? bp[0] : (c1 ? p : bp[1]);
    bp[0] = c0 ? p : bp[0];
    bd[2] = n2; bd[1] = n1; bd[0] = n0;
}

// one wave-argmin-pop round; returns 1 if this lane's head was popped
template<int DEPTH>
__device__ __forceinline__ int ext_round(float (&ld)[DEPTH], unsigned (&lp)[DEPTH],
                                         float &td, unsigned &tp, const int lane) {
    const unsigned key = __float_as_uint(ld[0]);
    unsigned m = key;
    m = dpp_umin<0xB1>(m);  m = dpp_umin<0x4E>(m);
    m = dpp_umin<0x141>(m); m = dpp_umin<0x140>(m);
    { unsigned t = __shfl_xor(m, 16); m = m < t ? m : t;
      t = __shfl_xor(m, 32);          m = m < t ? m : t; }
    const unsigned long long mk = __ballot(key == m);
    const int src = __ffsll(mk) - 1;          // lowest lane holding the min
    td = __uint_as_float(m);
    tp = __shfl(lp[0], src);
    if (lane == src) {
#pragma unroll
        for (int j = 0; j < DEPTH - 1; ++j) { ld[j] = ld[j + 1]; lp[j] = lp[j + 1]; }
        ld[DEPTH - 1] = FLT_BIG;
        return 1;
    }
    return 0;
}

template<int DEPTH>
__device__ __forceinline__ int extract8(float (&ld)[DEPTH], unsigned (&lp)[DEPTH],
                                        float (&td)[8], unsigned (&tp)[8], const int lane) {
    int pops = 0;
#pragma unroll
    for (int k = 0; k < 8; ++k) pops += ext_round<DEPTH>(ld, lp, td[k], tp[k], lane);
    return pops;
}

// full-rescan exact fallback for one row (rare: P~1.4%/row)
__device__ __forceinline__ void fallback_row(const f32x4* a4, const float2 g,
                                             float (&td)[8], unsigned (&tp)[8], const int lane) {
    float    fd[8];
    unsigned fp[8];
#pragma unroll
    for (int i = 0; i < 8; ++i) { fd[i] = FLT_BIG; fp[i] = 0u; }
    for (int it = 0; it < 16; ++it) {
        const f32x4 vv = a4[it * 64 + lane];
#pragma unroll
        for (int h = 0; h < 2; ++h) {
            const float ax = h ? vv.z : vv.x;
            const float ay = h ? vv.w : vv.y;
            const float ddx = ax - g.x, ddy = ay - g.y;
            const float d = __fadd_rn(__fmul_rn(ddx, ddx), __fmul_rn(ddy, ddy));
            if (d < fd[7]) {
                const unsigned p = pack2(ax, ay);
#pragma unroll
                for (int j = 7; j >= 1; --j) {
                    const bool s1 = fd[j - 1] > d;
                    const bool s2 = fd[j] > d;
                    const float    nd = s1 ? fd[j - 1] : (s2 ? d : fd[j]);
                    const unsigned np = s1 ? fp[j - 1] : (s2 ? p : fp[j]);
                    fd[j] = nd; fp[j] = np;
                }
                if (fd[0] > d) { fd[0] = d; fp[0] = p; }
            }
        }
    }
    (void)extract8<8>(fd, fp, td, tp, lane);
}

// ---------------------------------------------------------------------------
// Persistent fused kernel: 512 blocks x 512 threads (all-resident), each wave
// processes 8 rows (stride 4096). buf[16] holds one full row; while processing
// row r's chunk `it` the SAME slot is refilled with row r+1's chunk `it`, so a
// full 16 KB of the next row is in flight during the no-memory tail
// (extraction/softmax/MLP) -> per-wave load issue never pauses.
// No barriers in the row loop: each wave has its OWN h1 tile (8 k-rows; MFMA
// B-cols 8..15 duplicate cols 0..7 and are never stored). W2 staged bf16+swz
// once per block (amortized over 8 rows/wave).
// ---------------------------------------------------------------------------
__global__ void __launch_bounds__(512, 4) fused_anchor_mlp(
    const float* __restrict__ Gl, const float* __restrict__ ancL,
    const float* __restrict__ W1, const float* __restrict__ b1,
    const float* __restrict__ W2, const float* __restrict__ b2,
    float* __restrict__ out)
{
    __shared__ uint4  w2s[2048];      // 128 rows x 16 slots bf16x8, 32 KB
    __shared__ uint4  h1s4[1024];     // 8 waves x 8 k-rows x 16 slots, 16 KB
    __shared__ float4 b2s4[32];       // 512 B

    const int tid  = threadIdx.x;
    const int wave = tid >> 6;
    const int lane = tid & 63;
    const int wg   = (blockIdx.x << 3) + wave;   // wave-slot 0..4095

    // --- stage W2 (f32 -> bf16, phys_slot = slot ^ (row&7)) + b2; one barrier ---
    {
        const float4* w2f = reinterpret_cast<const float4*>(W2);
        for (int i = tid; i < 2048; i += 512) {
            const float4 lo = w2f[i * 2], hi = w2f[i * 2 + 1];
            uint4 u;
            u.x = pack2(lo.x, lo.y); u.y = pack2(lo.z, lo.w);
            u.z = pack2(hi.x, hi.y); u.w = pack2(hi.z, hi.w);
            w2s[(i & ~15) | ((i & 15) ^ ((i >> 4) & 7))] = u;
        }
        if (tid < 32) b2s4[tid] = reinterpret_cast<const float4*>(b2)[tid];
    }
    __syncthreads();   // the ONLY barrier; crossed before streaming starts

    const float2* Gl2 = reinterpret_cast<const float2*>(Gl);
    const f32x4*  aCur = reinterpret_cast<const f32x4*>(ancL) + (size_t)wg * (NM / 2);
    const size_t  STEP = (size_t)ROWSTEP * (NM / 2);

    const float4 w1v = reinterpret_cast<const float4*>(W1)[lane];
    const float2 b1v = reinterpret_cast<const float2*>(b1)[lane];
    unsigned* h1w = reinterpret_cast<unsigned*>(h1s4 + (wave << 7));
    const uint4* h1b = h1s4 + (wave << 7);
    const int bslot = lane >> 4, bxor = lane & 7;

    float2 gCur = Gl2[wg];

    // prologue: the whole first row in flight
    f32x4 buf[16];
#pragma unroll
    for (int j = 0; j < 16; ++j) buf[j] = aCur[j * 64 + lane];

    for (int r = 0; r < ROWS_PER_WAVE; ++r) {
        const int row = wg + r * ROWSTEP;
        const f32x4* aNext = aCur + STEP;
        const bool pf = (r < ROWS_PER_WAVE - 1);
        float2 gNext = gCur;
        if (pf) gNext = Gl2[row + ROWSTEP];      // issued early, used next iter

        // --- stream: consume row r from buf, refill slots with row r+1 ---
        float    bd[3];
        unsigned bp[3];
#pragma unroll
        for (int i = 0; i < 3; ++i) { bd[i] = FLT_BIG; bp[i] = 0u; }

#pragma unroll
        for (int it = 0; it < 16; ++it) {
            const f32x4 v = buf[it];
            if (pf) buf[it] = aNext[it * 64 + lane];
            const float dx0 = v.x - gCur.x, dy0 = v.y - gCur.y;
            const float dx1 = v.z - gCur.x, dy1 = v.w - gCur.y;
            // bit-identical to numpy: no fma contraction
            const float d0 = __fadd_rn(__fmul_rn(dx0, dx0), __fmul_rn(dy0, dy0));
            const float d1 = __fadd_rn(__fmul_rn(dx1, dx1), __fmul_rn(dy1, dy1));
            ins3(bd, bp, d0, pack2(v.x, v.y));
            ins3(bd, bp, d1, pack2(v.z, v.w));
        }

        // --- extraction: 8 rounds of DPP-argmin over lane heads ---
        float    td[8];
        unsigned tp[8];
        const int pops = extract8<3>(bd, bp, td, tp, lane);

        // --- exactness fallback (P~1.4%/row): some lane had all 3 popped ---
        if (__ballot(pops == 3)) fallback_row(aCur, gCur, td, tp, lane);

        // --- softmax(d2/tau); wsel for this lane's D column (k = lane&7) ---
        const float mx = td[7];
        float ek[8], ssum = 0.f;
#pragma unroll
        for (int k = 0; k < 8; ++k) { ek[k] = __expf((td[k] - mx) * (1.0f / TAU)); ssum += ek[k]; }
        const float inv = 1.0f / ssum;
        float wsel = 0.f;
#pragma unroll
        for (int k = 0; k < 8; ++k) wsel = ((lane & 7) == k) ? ek[k] * inv : wsel;

        // --- layer 1: lane owns e0=2*lane, e1=2*lane+1; own 8-row tile ---
#pragma unroll
        for (int k = 0; k < 8; ++k) {
            const unsigned pk = tp[k];
            const float ax = __uint_as_float(pk << 16);          // bf16 -> f32 exact
            const float ay = __uint_as_float(pk & 0xFFFF0000u);
            const float x0 = fmaf(ax, w1v.x, fmaf(ay, w1v.y, b1v.x));
            const float x1 = fmaf(ax, w1v.z, fmaf(ay, w1v.w, b1v.y));
            h1w[(k << 6) + ((((lane >> 2) ^ k) << 2) | (lane & 3))] =
                pack2(gelu_tanh(x0), gelu_tanh(x1));
        }
        // same-wave LDS write->read: compiler inserts lgkmcnt wait; no barrier

        // --- B fragments: col n = lane&15; rows 8..15 duplicate 0..7 (discarded) ---
        const int brow = (lane & 7) * 16;
        bf16x8 bq0 = __builtin_bit_cast(bf16x8, h1b[brow + (( 0 + bslot) ^ bxor)]);
        bf16x8 bq1 = __builtin_bit_cast(bf16x8, h1b[brow + (( 4 + bslot) ^ bxor)]);
        bf16x8 bq2 = __builtin_bit_cast(bf16x8, h1b[brow + (( 8 + bslot) ^ bxor)]);
        bf16x8 bq3 = __builtin_bit_cast(bf16x8, h1b[brow + ((12 + bslot) ^ bxor)]);

        // --- MFMA: all 8 f-tiles for this row ---
        const size_t outbase = (size_t)row * NEMB;
#pragma unroll 2
        for (int ft = 0; ft < 8; ++ft) {
            const int arow = (ft * 16 + (lane & 15)) * 16;
            f32x4 acc = {0.f, 0.f, 0.f, 0.f};
            acc = __builtin_amdgcn_mfma_f32_16x16x32_bf16(
                      __builtin_bit_cast(bf16x8, w2s[arow + (( 0 + bslot) ^ bxor)]), bq0, acc, 0, 0, 0);
            acc = __builtin_amdgcn_mfma_f32_16x16x32_bf16(
                      __builtin_bit_cast(bf16x8, w2s[arow + (( 4 + bslot) ^ bxor)]), bq1, acc, 0, 0, 0);
            acc = __builtin_amdgcn_mfma_f32_16x16x32_bf16(
                      __builtin_bit_cast(bf16x8, w2s[arow + (( 8 + bslot) ^ bxor)]), bq2, acc, 0, 0, 0);
            acc = __builtin_amdgcn_mfma_f32_16x16x32_bf16(
                      __builtin_bit_cast(bf16x8, w2s[arow + ((12 + bslot) ^ bxor)]), bq3, acc, 0, 0, 0);

            // D: row f = ft*16 + (lane>>4)*4 + j, col = lane&15
            const float4 b2v = b2s4[ft * 4 + (lane >> 4)];
            float s0 = gelu_tanh(acc[0] + b2v.x) * wsel;
            float s1 = gelu_tanh(acc[1] + b2v.y) * wsel;
            float s2 = gelu_tanh(acc[2] + b2v.z) * wsel;
            float s3 = gelu_tanh(acc[3] + b2v.w) * wsel;
            // sum over 8 k-slots (DPP stays within each 8-lane group)
            s0 = dpp_fadd<0xB1>(s0); s0 = dpp_fadd<0x4E>(s0); s0 = dpp_fadd<0x141>(s0);
            s1 = dpp_fadd<0xB1>(s1); s1 = dpp_fadd<0x4E>(s1); s1 = dpp_fadd<0x141>(s1);
            s2 = dpp_fadd<0xB1>(s2); s2 = dpp_fadd<0x4E>(s2); s2 = dpp_fadd<0x141>(s2);
            s3 = dpp_fadd<0xB1>(s3); s3 = dpp_fadd<0x4E>(s3); s3 = dpp_fadd<0x141>(s3);
            if ((lane & 15) == 0)
                *reinterpret_cast<float4*>(&out[outbase + ft * 16 + ((lane >> 4) << 2)]) =
                    make_float4(s0, s1, s2, s3);
        }

        aCur = aNext;
        gCur = gNext;
    }
}

extern "C" void kernel_launch(void* const* d_in, const int* in_sizes, int n_in,
                              void* d_out, int out_size, void* d_ws, size_t ws_size,
                              hipStream_t stream)
{
    const float* Gl  = (const float*)d_in[0];
    const float* anc = (const float*)d_in[1];
    const float* W1  = (const float*)d_in[2];
    const float* b1  = (const float*)d_in[3];
    const float* W2  = (const float*)d_in[4];
    const float* b2  = (const float*)d_in[5];
    float* outp = (float*)d_out;

    fused_anchor_mlp<<<512, 512, 0, stream>>>(Gl, anc, W1, b1, W2, b2, outp);
}

// Round 12
// 132.799 us; speedup vs baseline: 1.9598x; 1.9598x over previous
//
#include <hip/hip_runtime.h>
#include <hip/hip_bf16.h>
#include <math.h>

#define NB   32768
#define NM   2048
#define NEMB 128
#define NK   8
#define TAU  0.3f
#define FLT_BIG 3.402823466e38f

typedef __attribute__((ext_vector_type(8))) short bf16x8;
typedef __attribute__((ext_vector_type(4))) float f32x4;

// tanh-form GELU: x * sigmoid(2*0.79788456*(x+0.044715 x^3)), branch-free.
__device__ __forceinline__ float gelu_tanh(float x) {
    const float x2 = x * x;
    const float u  = fmaf(0.044715f, x2, 1.0f);
    const float a  = x * u * (-2.3022082f);          // -2*0.79788456*log2(e)
    const float e  = __builtin_amdgcn_exp2f(a);      // exp(-2t)
    const float r  = __builtin_amdgcn_rcpf(e + 1.0f);
    return x * r;                                    // x * sigmoid(2t)
}
// f32 pair -> packed bf16 (RNE): (bf16(hi)<<16)|bf16(lo), 1 v_cvt_pk_bf16_f32
__device__ __forceinline__ unsigned pack2(float lo, float hi) {
    __hip_bfloat162 b = __float22bfloat162_rn(make_float2(lo, hi));
    return *reinterpret_cast<unsigned*>(&b);
}

// DPP helpers: quad_perm xor1=0xB1, xor2=0x4E, row_half_mirror=0x141, row_mirror=0x140
template<int CTRL>
__device__ __forceinline__ unsigned dpp_umin(unsigned v) {
    const unsigned t = (unsigned)__builtin_amdgcn_update_dpp(0, (int)v, CTRL, 0xF, 0xF, true);
    return v < t ? v : t;
}
template<int CTRL>
__device__ __forceinline__ float dpp_fadd(float v) {
    const float t = __int_as_float(__builtin_amdgcn_update_dpp(0, __float_as_int(v), CTRL, 0xF, 0xF, true));
    return v + t;
}

// sorted top-3 insert (values via fmed3, payload via cndmask)
__device__ __forceinline__ void ins3(float (&bd)[3], unsigned (&bp)[3], float d, unsigned p) {
    const bool c0 = d < bd[0], c1 = d < bd[1], c2 = d < bd[2];
    const float n2 = __builtin_amdgcn_fmed3f(d, bd[1], bd[2]);
    const float n1 = __builtin_amdgcn_fmed3f(d, bd[0], bd[1]);
    const float n0 = fminf(d, bd[0]);
    bp[2] = c1 ? bp[1] : (c2 ? p : bp[2]);
    bp[1] = c0 ? bp[0] : (c1 ? p : bp[1]);
    bp[0] = c0 ? p : bp[0];
    bd[2] = n2; bd[1] = n1; bd[0] = n0;
}

// one wave-argmin-pop round; returns 1 if this lane's head was popped
template<int DEPTH>
__device__ __forceinline__ int ext_round(float (&ld)[DEPTH], unsigned (&lp)[DEPTH],
                                         float &td, unsigned &tp, const int lane) {
    const unsigned key = __float_as_uint(ld[0]);
    unsigned m = key;
    m = dpp_umin<0xB1>(m);  m = dpp_umin<0x4E>(m);
    m = dpp_umin<0x141>(m); m = dpp_umin<0x140>(m);
    { unsigned t = __shfl_xor(m, 16); m = m < t ? m : t;
      t = __shfl_xor(m, 32);          m = m < t ? m : t; }
    const unsigned long long mk = __ballot(key == m);
    const int src = __ffsll(mk) - 1;          // lowest lane holding the min
    td = __uint_as_float(m);
    tp = __shfl(lp[0], src);
    if (lane == src) {
#pragma unroll
        for (int j = 0; j < DEPTH - 1; ++j) { ld[j] = ld[j + 1]; lp[j] = lp[j + 1]; }
        ld[DEPTH - 1] = FLT_BIG;
        return 1;
    }
    return 0;
}

template<int DEPTH>
__device__ __forceinline__ int extract8(float (&ld)[DEPTH], unsigned (&lp)[DEPTH],
                                        float (&td)[8], unsigned (&tp)[8], const int lane) {
    int pops = 0;
#pragma unroll
    for (int k = 0; k < 8; ++k) pops += ext_round<DEPTH>(ld, lp, td[k], tp[k], lane);
    return pops;
}

// full-rescan exact fallback for one row (rare: P~1.4%/row)
__device__ __forceinline__ void fallback_row(const f32x4* a4, const float2 g,
                                             float (&td)[8], unsigned (&tp)[8], const int lane) {
    float    fd[8];
    unsigned fp[8];
#pragma unroll
    for (int i = 0; i < 8; ++i) { fd[i] = FLT_BIG; fp[i] = 0u; }
    for (int it = 0; it < 16; ++it) {
        const f32x4 vv = a4[it * 64 + lane];
#pragma unroll
        for (int h = 0; h < 2; ++h) {
            const float ax = h ? vv.z : vv.x;
            const float ay = h ? vv.w : vv.y;
            const float ddx = ax - g.x, ddy = ay - g.y;
            const float d = __fadd_rn(__fmul_rn(ddx, ddx), __fmul_rn(ddy, ddy));
            if (d < fd[7]) {
                const unsigned p = pack2(ax, ay);
#pragma unroll
                for (int j = 7; j >= 1; --j) {
                    const bool s1 = fd[j - 1] > d;
                    const bool s2 = fd[j] > d;
                    const float    nd = s1 ? fd[j - 1] : (s2 ? d : fd[j]);
                    const unsigned np = s1 ? fp[j - 1] : (s2 ? p : fp[j]);
                    fd[j] = nd; fp[j] = np;
                }
                if (fd[0] > d) { fd[0] = d; fp[0] = p; }
            }
        }
    }
    (void)extract8<8>(fd, fp, td, tp, lane);
}

// ---------------------------------------------------------------------------
// Fused kernel, 512 threads = 8 waves = 8 rows/block (R9 structure).
// R12 change (single variable): the stream loads TWO dwordx4 per chunk per
// lane (lane and lane+64) with a 3-deep rolling pipeline -> 6 KB in flight
// per wave (2x R9), clearing the Little's-law margin (Sum over CU waves of
// in-flight bytes was right at the BW*latency product).
// Phase 1: unconditional per-lane sorted top-3 (fmed3 + packed-bf16 payload),
//   DPP-argmin extraction x8, full-rescan fallback (P~1.4%/row).
// Phase 2: softmax -> layer1 tanh-GELU -> bf16 h1 pair tile (LDS, swizzled)
//   -> mfma_f32_16x16x32_bf16 (A=W2 bf16 LDS) -> fused epilogue with DPP
//   k-reduction. Row-pairing: B cols 0..7 even row, 8..15 odd row.
// LDS 48.75 KB -> 3 blocks/CU = 24 waves/CU; VGPR budget ~82 < 85 cap.
// ---------------------------------------------------------------------------
__global__ void __launch_bounds__(512, 6) fused_anchor_mlp(
    const float* __restrict__ Gl, const float* __restrict__ ancL,
    const float* __restrict__ W1, const float* __restrict__ b1,
    const float* __restrict__ W2, const float* __restrict__ b2,
    float* __restrict__ out)
{
    __shared__ uint4  w2s[2048];      // 128 rows x 16 slots bf16x8, 32 KB
    __shared__ uint4  h1s4[1024];     // 4 pairs x 16 k-rows x 16 slots, 16 KB
    __shared__ float4 b2s4[32];       // 512 B
    __shared__ float  wts[8][8];      // softmax weights per row

    const int tid  = threadIdx.x;
    const int wave = tid >> 6;
    const int lane = tid & 63;
    const int pair = wave >> 1;
    const int half = wave & 1;
    const int rowbase = blockIdx.x << 3;
    const int row  = rowbase + wave;

    // --- stage W2 (f32 -> bf16, phys_slot = slot ^ (row&7)) ---
    {
        const float4* w2f = reinterpret_cast<const float4*>(W2);
        for (int i = tid; i < 2048; i += 512) {
            const float4 lo = w2f[i * 2], hi = w2f[i * 2 + 1];
            uint4 u;
            u.x = pack2(lo.x, lo.y); u.y = pack2(lo.z, lo.w);
            u.z = pack2(hi.x, hi.y); u.w = pack2(hi.z, hi.w);
            w2s[(i & ~15) | ((i & 15) ^ ((i >> 4) & 7))] = u;
        }
        if (tid < 32) b2s4[tid] = reinterpret_cast<const float4*>(b2)[tid];
    }
    // single __syncthreads below (after h1 writes) covers all staging

    // --- phase 1: stream anchors, 3-deep x 32B rolling pipeline, top-3/lane ---
    const float2 g = reinterpret_cast<const float2*>(Gl)[row];
    const f32x4* a4 = reinterpret_cast<const f32x4*>(ancL) + (size_t)row * (NM / 2);

    float    bd[3];
    unsigned bp[3];
#pragma unroll
    for (int i = 0; i < 3; ++i) { bd[i] = FLT_BIG; bp[i] = 0u; }

    // 8 chunks of 128 f32x4; lane owns a4[c*128+lane] (A) and a4[c*128+64+lane] (B)
    f32x4 bufA[3], bufB[3];
#pragma unroll
    for (int j = 0; j < 3; ++j) {
        bufA[j] = a4[j * 128 + lane];
        bufB[j] = a4[j * 128 + 64 + lane];
    }

#pragma unroll
    for (int it = 0; it < 8; ++it) {
        const int slot = it % 3;                 // static after full unroll
        const f32x4 vA = bufA[slot];
        const f32x4 vB = bufB[slot];
        if (it + 3 < 8) {
            bufA[slot] = a4[(it + 3) * 128 + lane];
            bufB[slot] = a4[(it + 3) * 128 + 64 + lane];
        }
        // bit-identical to numpy: no fma contraction
        const float dxA0 = vA.x - g.x, dyA0 = vA.y - g.y;
        const float dxA1 = vA.z - g.x, dyA1 = vA.w - g.y;
        const float dA0 = __fadd_rn(__fmul_rn(dxA0, dxA0), __fmul_rn(dyA0, dyA0));
        const float dA1 = __fadd_rn(__fmul_rn(dxA1, dxA1), __fmul_rn(dyA1, dyA1));
        const float dxB0 = vB.x - g.x, dyB0 = vB.y - g.y;
        const float dxB1 = vB.z - g.x, dyB1 = vB.w - g.y;
        const float dB0 = __fadd_rn(__fmul_rn(dxB0, dxB0), __fmul_rn(dyB0, dyB0));
        const float dB1 = __fadd_rn(__fmul_rn(dxB1, dxB1), __fmul_rn(dyB1, dyB1));
        // candidate index order: A-half (lane) before B-half (lane+64) per chunk
        ins3(bd, bp, dA0, pack2(vA.x, vA.y));
        ins3(bd, bp, dA1, pack2(vA.z, vA.w));
        ins3(bd, bp, dB0, pack2(vB.x, vB.y));
        ins3(bd, bp, dB1, pack2(vB.z, vB.w));
    }

    // --- extraction: 8 rounds of DPP-argmin over lane heads ---
    float    td[8];
    unsigned tp[8];
    const int pops = extract8<3>(bd, bp, td, tp, lane);

    // --- exactness fallback (P~1.4%/row): some lane had all 3 popped ---
    if (__ballot(pops == 3)) fallback_row(a4, g, td, tp, lane);

    // --- softmax(d2/tau); publish weights for the pair epilogue ---
    const float mx = td[7];
    float ek[8], ssum = 0.f;
#pragma unroll
    for (int k = 0; k < 8; ++k) { ek[k] = __expf((td[k] - mx) * (1.0f / TAU)); ssum += ek[k]; }
    const float inv = 1.0f / ssum;
    float wv = 0.f;
#pragma unroll
    for (int k = 0; k < 8; ++k) wv = (lane == k) ? ek[k] * inv : wv;
    if (lane < 8) wts[wave][lane] = wv;

    // --- layer 1: lane owns e0=2*lane, e1=2*lane+1; write to pair tile ---
    const float4 w1v = reinterpret_cast<const float4*>(W1)[lane];
    const float2 b1v = reinterpret_cast<const float2*>(b1)[lane];
    unsigned* h1w = reinterpret_cast<unsigned*>(h1s4 + (pair << 8));
#pragma unroll
    for (int k = 0; k < 8; ++k) {
        const unsigned pk = tp[k];
        const float ax = __uint_as_float(pk << 16);          // bf16 -> f32 exact
        const float ay = __uint_as_float(pk & 0xFFFF0000u);
        const float x0 = fmaf(ax, w1v.x, fmaf(ay, w1v.y, b1v.x));
        const float x1 = fmaf(ax, w1v.z, fmaf(ay, w1v.w, b1v.y));
        const int r = (half << 3) + k;   // row in pair tile; swizzle key = r&7 = k
        h1w[(r << 6) + ((((lane >> 2) ^ k) << 2) | (lane & 3))] = pack2(gelu_tanh(x0), gelu_tanh(x1));
    }
    __syncthreads();

    // --- B fragments from pair tile: col n = lane&15 (0..7 even, 8..15 odd) ---
    const uint4* h1b = h1s4 + (pair << 8);
    const int bslot = lane >> 4, bxor = lane & 7, brow = (lane & 15) * 16;
    bf16x8 bq0 = __builtin_bit_cast(bf16x8, h1b[brow + (( 0 + bslot) ^ bxor)]);
    bf16x8 bq1 = __builtin_bit_cast(bf16x8, h1b[brow + (( 4 + bslot) ^ bxor)]);
    bf16x8 bq2 = __builtin_bit_cast(bf16x8, h1b[brow + (( 8 + bslot) ^ bxor)]);
    bf16x8 bq3 = __builtin_bit_cast(bf16x8, h1b[brow + ((12 + bslot) ^ bxor)]);

    // weight for this lane's D column
    const float wsel = wts[(pair << 1) | ((lane >> 3) & 1)][lane & 7];

    // --- MFMA: this wave does f-tiles half*4 .. half*4+3 for BOTH rows ---
#pragma unroll 2
    for (int i = 0; i < 4; ++i) {
        const int ft = (half << 2) + i;
        const int arow = (ft * 16 + (lane & 15)) * 16;
        f32x4 acc = {0.f, 0.f, 0.f, 0.f};
        acc = __builtin_amdgcn_mfma_f32_16x16x32_bf16(
                  __builtin_bit_cast(bf16x8, w2s[arow + (( 0 + bslot) ^ bxor)]), bq0, acc, 0, 0, 0);
        acc = __builtin_amdgcn_mfma_f32_16x16x32_bf16(
                  __builtin_bit_cast(bf16x8, w2s[arow + (( 4 + bslot) ^ bxor)]), bq1, acc, 0, 0, 0);
        acc = __builtin_amdgcn_mfma_f32_16x16x32_bf16(
                  __builtin_bit_cast(bf16x8, w2s[arow + (( 8 + bslot) ^ bxor)]), bq2, acc, 0, 0, 0);
        acc = __builtin_amdgcn_mfma_f32_16x16x32_bf16(
                  __builtin_bit_cast(bf16x8, w2s[arow + ((12 + bslot) ^ bxor)]), bq3, acc, 0, 0, 0);

        // D: row f = ft*16 + (lane>>4)*4 + j, col = lane&15
        const float4 b2v = b2s4[ft * 4 + (lane >> 4)];
        float s0 = gelu_tanh(acc[0] + b2v.x) * wsel;
        float s1 = gelu_tanh(acc[1] + b2v.y) * wsel;
        float s2 = gelu_tanh(acc[2] + b2v.z) * wsel;
        float s3 = gelu_tanh(acc[3] + b2v.w) * wsel;
        // sum over the 8 k-slots (lanes sharing lane&~7) via DPP adds
        s0 = dpp_fadd<0xB1>(s0); s0 = dpp_fadd<0x4E>(s0); s0 = dpp_fadd<0x141>(s0);
        s1 = dpp_fadd<0xB1>(s1); s1 = dpp_fadd<0x4E>(s1); s1 = dpp_fadd<0x141>(s1);
        s2 = dpp_fadd<0xB1>(s2); s2 = dpp_fadd<0x4E>(s2); s2 = dpp_fadd<0x141>(s2);
        s3 = dpp_fadd<0xB1>(s3); s3 = dpp_fadd<0x4E>(s3); s3 = dpp_fadd<0x141>(s3);
        if ((lane & 7) == 0) {
            const int which = (lane >> 3) & 1;   // 0 = row even, 1 = row odd
            const size_t ob = (size_t)(rowbase + (pair << 1) + which) * NEMB
                              + ft * 16 + ((lane >> 4) << 2);
            *reinterpret_cast<float4*>(&out[ob]) = make_float4(s0, s1, s2, s3);
        }
    }
}

extern "C" void kernel_launch(void* const* d_in, const int* in_sizes, int n_in,
                              void* d_out, int out_size, void* d_ws, size_t ws_size,
                              hipStream_t stream)
{
    const float* Gl  = (const float*)d_in[0];
    const float* anc = (const float*)d_in[1];
    const float* W1  = (const float*)d_in[2];
    const float* b1  = (const float*)d_in[3];
    const float* W2  = (const float*)d_in[4];
    const float* b2  = (const float*)d_in[5];
    float* outp = (float*)d_out;

    fused_anchor_mlp<<<NB / 8, 512, 0, stream>>>(Gl, anc, W1, b1, W2, b2, outp);
}